// Round 1
// baseline (8545.088 us; speedup 1.0000x reference)
//
#include <hip/hip_runtime.h>

// ============================================================================
// Compile-time replication of the reference's Wigner-3j / tensor-product
// structure (Racah formula + e3nn real<->complex change of basis), so that
// all loop indices in the kernels are compile-time constants (registers, no
// scratch) and w3 zeros are skipped with `if constexpr`.
// ============================================================================

constexpr double cfact(int n){ double r = 1.0; for (int i = 2; i <= n; ++i) r *= (double)i; return r; }

constexpr double csqrt(double x){
  if (x <= 0.0) return 0.0;
  double g = x > 1.0 ? x : 1.0;
  for (int i = 0; i < 100; ++i) g = 0.5*(g + x/g);
  return g;
}

struct CD { double re, im; };

constexpr double su2_cg(int j1,int j2,int j3,int m1,int m2){
  int m3 = m1 + m2;
  if (m3 < -j3 || m3 > j3) return 0.0;
  double p1 = (2.0*j3+1.0)*cfact(j1+j2-j3)*cfact(j1-j2+j3)*cfact(-j1+j2+j3)/cfact(j1+j2+j3+1);
  double p2 = cfact(j1+m1)*cfact(j1-m1)*cfact(j2+m2)*cfact(j2-m2)*cfact(j3+m3)*cfact(j3-m3);
  double pref = csqrt(p1*p2);
  int k0 = 0;
  if (j2-j3-m1 > k0) k0 = j2-j3-m1;
  if (j1+m2-j3 > k0) k0 = j1+m2-j3;
  int k1 = j1+j2-j3;
  if (j1-m1 < k1) k1 = j1-m1;
  if (j2+m2 < k1) k1 = j2+m2;
  double s = 0.0;
  for (int k = k0; k <= k1; ++k){
    double t = 1.0/(cfact(k)*cfact(j1+j2-j3-k)*cfact(j1-m1-k)*cfact(j2+m2-k)
                    *cfact(j3-j2+m1+k)*cfact(j3-j1-m2+k));
    s += (k & 1) ? -t : t;
  }
  return pref*s;
}

// Row r of e3nn's real->complex change-of-basis Q matrix for degree l,
// including the (-i)^l phase. At most 2 nonzero columns.
struct QRow { int n; int col[2]; CD q[2]; };
constexpr QRow qrow(int l, int r){
  QRow R{};
  constexpr double s2 = 0.70710678118654752440;
  int m = r - l;
  if (m < 0){
    R.n = 2;
    R.col[0] = l - m; R.q[0] = CD{s2, 0.0};     // q[l+m, l+|m|] = 1/sqrt2
    R.col[1] = l + m; R.q[1] = CD{0.0, -s2};    // q[l+m, l-|m|] = -i/sqrt2
  } else if (m == 0){
    R.n = 1; R.col[0] = l; R.q[0] = CD{1.0, 0.0};
  } else {
    double sg = (m & 1) ? -1.0 : 1.0;
    R.n = 2;
    R.col[0] = l + m; R.q[0] = CD{sg*s2, 0.0};
    R.col[1] = l - m; R.q[1] = CD{0.0, sg*s2};
  }
  int ph = l & 3;   // multiply by (-i)^l
  for (int t = 0; t < R.n; ++t){
    double a = R.q[t].re, b = R.q[t].im;
    if      (ph == 1) R.q[t] = CD{ b, -a};
    else if (ph == 2) R.q[t] = CD{-a, -b};
    else if (ph == 3) R.q[t] = CD{-b,  a};
  }
  return R;
}

constexpr int MAXNZ = 160;
struct W3NZ { int n; int ijk[MAXNZ]; float v[MAXNZ]; };

constexpr W3NZ build_w3(int l1,int l2,int l3){
  double re[7][7][7]{};
  int d1 = 2*l1+1, d2 = 2*l2+1, d3 = 2*l3+1;
  for (int i = 0; i < d1; ++i) for (int k = 0; k < d2; ++k){
    int m1 = i - l1, m2 = k - l2, m3 = m1 + m2;
    if (m3 < -l3 || m3 > l3) continue;
    int n = m3 + l3;
    double cg = su2_cg(l1,l2,l3,m1,m2);
    if (cg == 0.0) continue;
    QRow q1 = qrow(l1,i), q2 = qrow(l2,k), q3 = qrow(l3,n);
    for (int a = 0; a < q1.n; ++a) for (int b = 0; b < q2.n; ++b) for (int c = 0; c < q3.n; ++c){
      CD A = q1.q[a], B = q2.q[b], C = q3.q[c];
      C.im = -C.im;                                    // conj(Q3)
      CD AB{A.re*B.re - A.im*B.im, A.re*B.im + A.im*B.re};
      double tre = AB.re*C.re - AB.im*C.im;            // real part of A*B*conj(C)
      re[q1.col[a]][q2.col[b]][q3.col[c]] += tre*cg;
    }
  }
  double nrm = 0.0;
  for (int i = 0; i < d1; ++i) for (int j = 0; j < d2; ++j) for (int k = 0; k < d3; ++k)
    nrm += re[i][j][k]*re[i][j][k];
  nrm = csqrt(nrm);
  W3NZ R{};
  for (int i = 0; i < d1; ++i) for (int j = 0; j < d2; ++j) for (int k = 0; k < d3; ++k){
    double val = re[i][j][k]/nrm;
    if (val > 1e-9 || val < -1e-9){
      R.ijk[R.n] = i | (j << 3) | (k << 6);
      R.v[R.n]   = (float)val;
      R.n++;
    }
  }
  return R;
}

// Canonical enumeration of the 34 (l1,l2,l3) triangle-valid combos (l<=3).
struct C3 { int l1,l2,l3; };
constexpr C3 combo_at(int cid){
  int c = 0;
  for (int a = 0; a <= 3; ++a) for (int b = 0; b <= 3; ++b){
    int lmin = a > b ? a-b : b-a;
    int lmax = a+b > 3 ? 3 : a+b;
    for (int lo = lmin; lo <= lmax; ++lo){ if (c == cid) return C3{a,b,lo}; ++c; }
  }
  return C3{0,0,0};
}
constexpr int cid_of(int l1,int l2,int l3){
  int c = 0;
  for (int a = 0; a <= 3; ++a) for (int b = 0; b <= 3; ++b){
    int lmin = a > b ? a-b : b-a;
    int lmax = a+b > 3 ? 3 : a+b;
    for (int lo = lmin; lo <= lmax; ++lo){ if (a==l1 && b==l2 && lo==l3) return c; ++c; }
  }
  return -1;
}

template<int C> struct W3Tab {
  static constexpr W3NZ v = build_w3(combo_at(C).l1, combo_at(C).l2, combo_at(C).l3);
};

// ----------------------------------------------------------------------------
// Tensor-product path tables (replicates _build_tp exactly, incl. wof order
// and element path-normalization). scale = sqrt((2lo+1)/fan) * 0.25, folding
// the 1/sqrt(16) neighbor normalization of the *input* node features.
// ----------------------------------------------------------------------------
struct Irr { int mul, l, p; };
constexpr Irr IRR_SH_A[4]  = {{1,0,1},{1,1,-1},{1,2,1},{1,3,-1}};
constexpr Irr IRR_MID_A[8] = {{5,0,-1},{5,0,1},{5,1,-1},{5,1,1},{5,2,-1},{5,2,1},{5,3,-1},{5,3,1}};
constexpr Irr IRR_OUT_A[1] = {{64,0,1}};

struct PathT { int o1,m1,l1,o2,l2,oo,mo,lo,ioi,wof,cid; float scale; };
struct TPD   { int np; int d1tot, d2tot, dotot, wtot; PathT p[68]; };

constexpr TPD build_tp(const Irr* I1, int n1, const Irr* I2, int n2, const Irr* IO, int no){
  TPD T{};
  int o1s[8]{}, o2s[8]{}, oos[8]{};
  { int off=0; for (int i=0;i<n1;++i){ o1s[i]=off; off += I1[i].mul*(2*I1[i].l+1); } T.d1tot=off; }
  { int off=0; for (int i=0;i<n2;++i){ o2s[i]=off; off += I2[i].mul*(2*I2[i].l+1); } T.d2tot=off; }
  { int off=0; for (int i=0;i<no;++i){ oos[i]=off; off += IO[i].mul*(2*IO[i].l+1); } T.dotot=off; }
  int wof = 0;
  for (int i1=0;i1<n1;++i1) for (int i2=0;i2<n2;++i2) for (int io=0;io<no;++io){
    int L1=I1[i1].l, L2=I2[i2].l, LO=IO[io].l;
    int dl = L1>L2 ? L1-L2 : L2-L1;
    if (IO[io].p == I1[i1].p*I2[i2].p && dl <= LO && LO <= L1+L2){
      PathT& P = T.p[T.np];
      P.o1=o1s[i1]; P.m1=I1[i1].mul; P.l1=L1;
      P.o2=o2s[i2]; P.l2=L2;
      P.oo=oos[io]; P.mo=IO[io].mul; P.lo=LO; P.ioi=io;
      P.wof=wof; P.cid=cid_of(L1,L2,LO);
      wof += I1[i1].mul * I2[i2].mul * IO[io].mul;
      T.np++;
    }
  }
  T.wtot = wof;
  for (int p = 0; p < T.np; ++p){
    int fan = 0;
    for (int q = 0; q < T.np; ++q) if (T.p[q].ioi == T.p[p].ioi) fan += T.p[q].m1;  // m2==1
    T.p[p].scale = (float)(csqrt((2.0*T.p[p].lo+1.0)/(double)fan) * 0.25);
  }
  return T;
}

template<int ID> struct TPSel;
template<> struct TPSel<0>{ static constexpr TPD v = build_tp(IRR_SH_A,4,  IRR_SH_A,4, IRR_MID_A,8); };
template<> struct TPSel<1>{ static constexpr TPD v = build_tp(IRR_MID_A,8, IRR_SH_A,4, IRR_MID_A,8); };
template<> struct TPSel<2>{ static constexpr TPD v = build_tp(IRR_MID_A,8, IRR_SH_A,4, IRR_OUT_A,1); };

static_assert(TPSel<0>::v.np == 34 && TPSel<0>::v.wtot == 170,  "TP_IN structure mismatch");
static_assert(TPSel<1>::v.np == 68 && TPSel<1>::v.wtot == 1700, "TP_LAYER structure mismatch");
static_assert(TPSel<2>::v.np == 4  && TPSel<2>::v.wtot == 1280, "TP_OUT structure mismatch");
static_assert(TPSel<0>::v.d1tot == 16 && TPSel<0>::v.dotot == 160, "dims");
static_assert(TPSel<1>::v.d1tot == 160 && TPSel<1>::v.dotot == 160, "dims");
static_assert(TPSel<2>::v.d1tot == 160 && TPSel<2>::v.dotot == 64, "dims");
static_assert(W3Tab<0>::v.n == 1, "w3(0,0,0)");
static_assert(W3Tab<cid_of(1,1,0)>::v.n == 3, "w3(1,1,0) diag");

constexpr int path_count_into(const TPD& T, int io){
  int c = 0; for (int q = 0; q < T.np; ++q) if (T.p[q].ioi == io) ++c; return c;
}
constexpr int out_off_of(const TPD& T, int io){
  for (int q = 0; q < T.np; ++q) if (T.p[q].ioi == io) return T.p[q].oo; return 0;
}
constexpr Irr get_oi(int tpid, int io){ return tpid == 2 ? IRR_OUT_A[io] : IRR_MID_A[io]; }

// Compile-time for-loop (divide & conquer to keep instantiation depth low)
template<int V> struct IC { static constexpr int value = V; };
template<int I, int N, class F>
__device__ __forceinline__ void sfor(F&& f){
  if constexpr (N - I == 1){ f(IC<I>{}); }
  else if constexpr (N - I > 1){
    constexpr int M = I + (N - I)/2;
    sfor<I, M>(f);
    sfor<M, N>(f);
  }
}

// ============================================================================
// Kernels
// ============================================================================

__device__ __forceinline__ void sh16(float x, float y, float z, float* b){
  const float s3 = 1.7320508075688772f, s5 = 2.2360679774997896f, s7 = 2.6457513110645907f;
  const float c30 = 0.9128709291752769f;   // sqrt(5/6)
  const float c32 = 0.6123724356957945f;   // sqrt(3/8)
  float y2 = y*y, x2z2 = x*x + z*z;
  float sh20 = s3*x*z, sh21 = s3*x*y, sh22 = y2 - 0.5f*x2z2, sh23 = s3*y*z, sh24 = 0.5f*s3*(z*z - x*x);
  float sh30 = c30*(sh20*z + sh24*x);
  float sh31 = s5*sh20*y;
  float sh32 = c32*(4.0f*y2 - x2z2)*x;
  float sh33 = 0.5f*y*(2.0f*y2 - 3.0f*x2z2);
  float sh34 = c32*z*(4.0f*y2 - x2z2);
  float sh35 = s5*sh24*y;
  float sh36 = c30*(sh24*z - sh20*x);
  b[0]=1.0f; b[1]=s3*x; b[2]=s3*y; b[3]=s3*z;
  b[4]=s5*sh20; b[5]=s5*sh21; b[6]=s5*sh22; b[7]=s5*sh23; b[8]=s5*sh24;
  b[9]=s7*sh30; b[10]=s7*sh31; b[11]=s7*sh32; b[12]=s7*sh33; b[13]=s7*sh34; b[14]=s7*sh35; b[15]=s7*sh36;
}

__global__ void __launch_bounds__(256) k_sh_scatter(const float* __restrict__ evec,
    const int* __restrict__ dst, float* __restrict__ nodeA, int E){
  int e = blockIdx.x*256 + threadIdx.x;
  if (e >= E) return;
  float b[16];
  sh16(evec[3*(size_t)e], evec[3*(size_t)e+1], evec[3*(size_t)e+2], b);
  float* p = nodeA + (size_t)dst[e]*16;
  #pragma unroll
  for (int i = 0; i < 16; ++i) atomicAdd(p + i, b[i]);
}

// Generic fused tensor-product + scatter kernel. One thread per edge; PO
// selects the output-parity half (register-pressure split). a = raw gathered
// node features (1/sqrt(16) folded into path scale).
template<int TPID, int PO>
__global__ void __launch_bounds__(256, 2) k_tp(const float* __restrict__ nin,
    const float* __restrict__ evec, const int* __restrict__ src, const int* __restrict__ dst,
    const float* __restrict__ w, float* __restrict__ nout, int E)
{
  constexpr int D1TOT = TPSel<TPID>::v.d1tot;
  constexpr int DOTOT = TPSel<TPID>::v.dotot;
  constexpr int NIO   = (TPID == 2) ? 1 : 8;
  int e = blockIdx.x*256 + threadIdx.x;
  if (e >= E) return;
  float b[16];
  sh16(evec[3*(size_t)e], evec[3*(size_t)e+1], evec[3*(size_t)e+2], b);
  const float* __restrict__ arow = nin + (size_t)src[e]*D1TOT;
  float* __restrict__ orow = nout + (size_t)dst[e]*DOTOT;

  sfor<0, NIO>([&](auto IOC){
    constexpr int IO = decltype(IOC)::value;
    constexpr Irr OI = get_oi(TPID, IO);
    constexpr int NPIN = path_count_into(TPSel<TPID>::v, IO);
    if constexpr (OI.p == PO && NPIN > 0){
      constexpr int dd  = 2*OI.l + 1;
      constexpr int ACC = OI.mul * dd;
      float acc[ACC];
      #pragma unroll
      for (int i = 0; i < ACC; ++i) acc[i] = 0.0f;

      sfor<0, TPSel<TPID>::v.np>([&](auto PC){
        constexpr PathT P = TPSel<TPID>::v.p[decltype(PC)::value];
        if constexpr (P.ioi == IO){
          constexpr int d1 = 2*P.l1 + 1;
          float av[P.m1*d1];
          #pragma unroll
          for (int i = 0; i < P.m1*d1; ++i) av[i] = arow[P.o1 + i];
          float t[P.m1*dd];
          #pragma unroll
          for (int i = 0; i < P.m1*dd; ++i) t[i] = 0.0f;
          // sparse CG contraction: t[u,k] += a[u,i] * b[j] * w3[i,j,k]
          sfor<0, W3Tab<P.cid>::v.n>([&](auto NI){
            constexpr int ni  = decltype(NI)::value;
            constexpr int ijk = W3Tab<P.cid>::v.ijk[ni];
            constexpr int ii = ijk & 7, jj = (ijk >> 3) & 7, kk = ijk >> 6;
            constexpr float v = W3Tab<P.cid>::v.v[ni];
            float bv = b[P.o2 + jj] * v;
            #pragma unroll
            for (int u = 0; u < P.m1; ++u) t[u*dd + kk] += av[u*d1 + ii]*bv;
          });
          // weight mixing: acc[w,k] += scale * W[u,w] * t[u,k]  (uniform s_loads)
          #pragma unroll
          for (int u = 0; u < P.m1; ++u){
            #pragma unroll
            for (int wj = 0; wj < OI.mul; ++wj){
              float wv = w[P.wof + u*OI.mul + wj] * P.scale;
              #pragma unroll
              for (int k = 0; k < dd; ++k) acc[wj*dd + k] += wv * t[u*dd + k];
            }
          }
        }
      });

      constexpr int OB = out_off_of(TPSel<TPID>::v, IO);
      #pragma unroll
      for (int i = 0; i < ACC; ++i) atomicAdd(orow + OB + i, acc[i]);
    }
  });
}

// Final per-graph reduction: out[g,f] += nodeD[n,f] * (0.25 / sqrt(100) / 1e4)
__global__ void __launch_bounds__(256) k_graph(const float* __restrict__ nodeD,
    const int* __restrict__ batch, float* __restrict__ out, int N){
  int gid = blockIdx.x*256 + threadIdx.x;
  if (gid >= N*64) return;
  int n = gid >> 6, f = gid & 63;
  float v = nodeD[gid] * 2.5e-6f;
  atomicAdd(out + ((size_t)batch[n] << 6) + f, v);
}

// ============================================================================
extern "C" void kernel_launch(void* const* d_in, const int* in_sizes, int n_in,
                              void* d_out, int out_size, void* d_ws, size_t ws_size,
                              hipStream_t stream){
  const int*   eidx  = (const int*)d_in[0];
  const float* evec  = (const float*)d_in[1];
  const int*   batch = (const int*)d_in[2];
  const float* w_in  = (const float*)d_in[3];
  const float* w_ly  = (const float*)d_in[4];
  const float* w_out = (const float*)d_in[5];

  const int E = in_sizes[0]/2;   // 400000
  const int N = in_sizes[2];     // 25000
  const int* src = eidx;
  const int* dstp = eidx + E;

  float* nodeA = (float*)d_ws;                      // [N,16]
  float* nodeB = nodeA + (size_t)N*16;              // [N,160]
  float* nodeC = nodeB + (size_t)N*160;             // [N,160]
  float* nodeD = nodeC + (size_t)N*160;             // [N,64]

  hipMemsetAsync(d_ws, 0, (size_t)N*(16+160+160+64)*sizeof(float), stream);
  hipMemsetAsync(d_out, 0, (size_t)out_size*sizeof(float), stream);

  int nbE = (E + 255)/256;
  k_sh_scatter<<<nbE, 256, 0, stream>>>(evec, dstp, nodeA, E);
  k_tp<0,-1><<<nbE, 256, 0, stream>>>(nodeA, evec, src, dstp, w_in,  nodeB, E);
  k_tp<0, 1><<<nbE, 256, 0, stream>>>(nodeA, evec, src, dstp, w_in,  nodeB, E);
  k_tp<1,-1><<<nbE, 256, 0, stream>>>(nodeB, evec, src, dstp, w_ly,  nodeC, E);
  k_tp<1, 1><<<nbE, 256, 0, stream>>>(nodeB, evec, src, dstp, w_ly,  nodeC, E);
  k_tp<2, 1><<<nbE, 256, 0, stream>>>(nodeC, evec, src, dstp, w_out, nodeD, E);
  k_graph<<<((size_t)N*64 + 255)/256, 256, 0, stream>>>(nodeD, batch, (float*)d_out, N);
}